// Round 7
// baseline (229.807 us; speedup 1.0000x reference)
//
#include <hip/hip_runtime.h>

// NeuralHashVoxel round 7:
//  - stage-2 per-bin sort: bitonic -> 64-bucket LDS counting sort (6-bit
//    sub-Morton, 0.78-cell granularity) — same locality, ~1/5 the cost.
//  - validity bitmap pre-pass: 1 bit per hash bucket (idx>=0), built by one
//    streaming pass over fidx (96 MB). Main kernel probes L2-resident bitmap
//    (3 MB) and fetches idx+features only for valid (point,level) pairs
//    (16.8%) — cuts idx-table HBM demand 6x, relieving L3 thrash.

static constexpr int      NPTS  = 1048576;
static constexpr int      LVLS  = 6;
static constexpr int      NF    = 8;
static constexpr int      TTAB  = 524288;
static constexpr unsigned BTAB  = 4194304u;          // 2^22 buckets per level
static constexpr unsigned BMASK = BTAB - 1u;
static constexpr unsigned P0 = 73856093u, P1 = 19349669u, P2 = 83492791u;

static constexpr int NBIN = 4096;        // 16^3 Morton bins, cell = 3.125
static constexpr int SB   = 256;         // sort blocks
static constexpr int PPB  = NPTS / SB;   // 4096 points per sort block
static constexpr int ITER = PPB / 256;   // 16 per thread
static constexpr int BCAP = 512;         // stage-2 per-bin capacity (avg 256)

static constexpr int    BMW_L        = BTAB / 32;            // bitmap words/level
static constexpr size_t SORTED_BYTES = (size_t)NPTS * 16;
static constexpr size_t BM_BYTES     = (size_t)LVLS * BMW_L * 4;   // 3 MB

typedef float f4 __attribute__((ext_vector_type(4)));
typedef int   i4 __attribute__((ext_vector_type(4)));

// ---------------- bitmap build: 1 bit per bucket = (idx >= 0) --------------
__global__ __launch_bounds__(256) void bmbuild_k(const int* __restrict__ fidx,
                                                 unsigned* __restrict__ bm) {
    const int g = blockIdx.x * 256 + threadIdx.x;   // 786432 threads total
    const i4* p = (const i4*)(fidx + (size_t)g * 32);
    unsigned w = 0;
#pragma unroll
    for (int j = 0; j < 8; ++j) {
        const i4 v = __builtin_nontemporal_load(p + j);
        w |= (unsigned)(v.x >= 0) << (4 * j + 0);
        w |= (unsigned)(v.y >= 0) << (4 * j + 1);
        w |= (unsigned)(v.z >= 0) << (4 * j + 2);
        w |= (unsigned)(v.w >= 0) << (4 * j + 3);
    }
    bm[g] = w;
}

// ---------------- per-point computation, bitmap-gated -----------------------
__device__ __forceinline__ void nhv_point_bm(
    float qx, float qy, float qz,
    const float* __restrict__ feat, const int* __restrict__ fidx,
    const unsigned* __restrict__ bm, float acc[NF])
{
    float    fx[LVLS], fy[LVLS], fz[LVLS];
    unsigned h[LVLS];
#pragma unroll
    for (int i = 0; i < LVLS; ++i) {
        const float inv = 4.0f / (float)(1 << i);    // exact pow2: q*inv == q/res
        const float sx = qx * inv, sy = qy * inv, sz = qz * inv;
        const float bx = floorf(sx), by = floorf(sy), bz = floorf(sz);
        fx[i] = sx - bx; fy[i] = sy - by; fz[i] = sz - bz;
        h[i] = (unsigned)(int)bx * P0 + (unsigned)(int)by * P1 + (unsigned)(int)bz * P2;
    }

    // probe validity bitmap for all 6x8 corners (L2-resident, no HBM)
    unsigned vmask = 0;
#pragma unroll
    for (int i = 0; i < LVLS; ++i) {
        const unsigned* __restrict__ bl = bm + i * BMW_L;
        unsigned v = ~0u;
#pragma unroll
        for (int k = 0; k < 8; ++k) {
            unsigned key = h[i];
            if (k & 4) key += P0;
            if (k & 2) key += P1;
            if (k & 1) key += P2;
            key &= BMASK;
            v &= (bl[key >> 5] >> (key & 31u));
        }
        vmask |= (v & 1u) << i;
    }

#pragma unroll
    for (int f = 0; f < NF; ++f) acc[f] = 0.0f;

#pragma unroll
    for (int i = 0; i < LVLS; ++i) {
        if (vmask & (1u << i)) {   // all 8 corners valid -> idx in [0,T)
            const int* __restrict__ tab = fidx + (size_t)i * BTAB;
            int id[8];
#pragma unroll
            for (int k = 0; k < 8; ++k) {
                unsigned key = h[i];
                if (k & 4) key += P0;
                if (k & 2) key += P1;
                if (k & 1) key += P2;
                id[k] = tab[key & BMASK];
            }
            const float wxv[2] = {1.0f - fx[i], fx[i]};
            const float wyv[2] = {1.0f - fy[i], fy[i]};
            const float wzv[2] = {1.0f - fz[i], fz[i]};
            const float* __restrict__ fb = feat + (size_t)i * (TTAB * NF);
#pragma unroll
            for (int k = 0; k < 8; ++k) {
                const float c = wxv[(k >> 2) & 1] * wyv[(k >> 1) & 1] * wzv[k & 1];
                const float4* p = (const float4*)(fb + (size_t)id[k] * NF);
                const float4 lo = p[0];
                const float4 hi = p[1];
                acc[0] += c * lo.x; acc[1] += c * lo.y;
                acc[2] += c * lo.z; acc[3] += c * lo.w;
                acc[4] += c * hi.x; acc[5] += c * hi.y;
                acc[6] += c * hi.z; acc[7] += c * hi.w;
            }
        }
    }
}

// ---------------- per-point computation, plain (fallback) -------------------
__device__ __forceinline__ void nhv_point(
    float qx, float qy, float qz,
    const float* __restrict__ feat, const int* __restrict__ fidx, float acc[NF])
{
    float    fx[LVLS], fy[LVLS], fz[LVLS];
    unsigned h[LVLS];
#pragma unroll
    for (int i = 0; i < LVLS; ++i) {
        const float inv = 4.0f / (float)(1 << i);
        const float sx = qx * inv, sy = qy * inv, sz = qz * inv;
        const float bx = floorf(sx), by = floorf(sy), bz = floorf(sz);
        fx[i] = sx - bx; fy[i] = sy - by; fz[i] = sz - bz;
        h[i] = (unsigned)(int)bx * P0 + (unsigned)(int)by * P1 + (unsigned)(int)bz * P2;
    }
    int id[LVLS][8];
#pragma unroll
    for (int i = 0; i < LVLS; ++i) {
        const int* __restrict__ tab = fidx + (size_t)i * BTAB;
#pragma unroll
        for (int k = 0; k < 8; ++k) {
            unsigned key = h[i];
            if (k & 4) key += P0;
            if (k & 2) key += P1;
            if (k & 1) key += P2;
            id[i][k] = tab[key & BMASK];
        }
    }
#pragma unroll
    for (int f = 0; f < NF; ++f) acc[f] = 0.0f;
#pragma unroll
    for (int i = 0; i < LVLS; ++i) {
        int mn = id[i][0];
#pragma unroll
        for (int k = 1; k < 8; ++k) mn = min(mn, id[i][k]);
        if (mn > -1) {
            const float wxv[2] = {1.0f - fx[i], fx[i]};
            const float wyv[2] = {1.0f - fy[i], fy[i]};
            const float wzv[2] = {1.0f - fz[i], fz[i]};
            const float* __restrict__ fb = feat + (size_t)i * (TTAB * NF);
#pragma unroll
            for (int k = 0; k < 8; ++k) {
                const float c = wxv[(k >> 2) & 1] * wyv[(k >> 1) & 1] * wzv[k & 1];
                const float4* p = (const float4*)(fb + (size_t)id[i][k] * NF);
                const float4 lo = p[0];
                const float4 hi = p[1];
                acc[0] += c * lo.x; acc[1] += c * lo.y;
                acc[2] += c * lo.z; acc[3] += c * lo.w;
                acc[4] += c * hi.x; acc[5] += c * hi.y;
                acc[6] += c * hi.z; acc[7] += c * hi.w;
            }
        }
    }
}

// ---------------- binning ----------------
__device__ __forceinline__ unsigned expand4(unsigned v) {
    return (v & 1u) | ((v & 2u) << 2) | ((v & 4u) << 4) | ((v & 8u) << 6);
}
__device__ __forceinline__ unsigned bin_of(float x, float y, float z) {
    unsigned bx = min(15u, (unsigned)(int)(x * 0.32f));
    unsigned by = min(15u, (unsigned)(int)(y * 0.32f));
    unsigned bz = min(15u, (unsigned)(int)(z * 0.32f));
    return expand4(bx) | (expand4(by) << 1) | (expand4(bz) << 2);
}

// ---------------- sort stage 1 (no global atomics) ----------------
__global__ __launch_bounds__(256) void hist_k(const float* __restrict__ qp,
                                              unsigned* __restrict__ hist) {
    __shared__ unsigned lh[NBIN];
    const int b = blockIdx.x, t = threadIdx.x;
    for (int i = t; i < NBIN; i += 256) lh[i] = 0u;
    __syncthreads();
    const int base = b * PPB;
#pragma unroll
    for (int i = 0; i < ITER; ++i) {
        const int p = base + i * 256 + t;
        atomicAdd(&lh[bin_of(qp[3*p], qp[3*p+1], qp[3*p+2])], 1u);
    }
    __syncthreads();
    for (int i = t; i < NBIN; i += 256) hist[(size_t)b * NBIN + i] = lh[i];
}

__global__ __launch_bounds__(256) void colscan_k(unsigned* __restrict__ hist,
                                                 unsigned* __restrict__ binbase) {
    const int bin = blockIdx.x * 256 + threadIdx.x;   // 16 blocks
    unsigned run = 0;
    for (int b = 0; b < SB; ++b) {
        const unsigned v = hist[(size_t)b * NBIN + bin];
        hist[(size_t)b * NBIN + bin] = run;
        run += v;
    }
    binbase[bin] = run;
}

__global__ __launch_bounds__(256) void binscan_k(unsigned* __restrict__ binbase) {
    __shared__ unsigned tot[256];
    const int t = threadIdx.x;
    unsigned v[16];
    unsigned s = 0;
#pragma unroll
    for (int i = 0; i < 16; ++i) { v[i] = s; s += binbase[t * 16 + i]; }
    tot[t] = s;
    __syncthreads();
    for (int d = 1; d < 256; d <<= 1) {
        const unsigned x = (t >= d) ? tot[t - d] : 0u;
        __syncthreads();
        tot[t] += x;
        __syncthreads();
    }
    const unsigned cb = tot[t] - s;
#pragma unroll
    for (int i = 0; i < 16; ++i) binbase[t * 16 + i] = cb + v[i];
}

__global__ __launch_bounds__(256) void scatter_k(const float* __restrict__ qp,
                                                 const unsigned* __restrict__ hist,
                                                 const unsigned* __restrict__ binbase,
                                                 float4* __restrict__ sorted) {
    __shared__ unsigned cur[NBIN];
    const int b = blockIdx.x, t = threadIdx.x;
    for (int i = t; i < NBIN; i += 256)
        cur[i] = binbase[i] + hist[(size_t)b * NBIN + i];
    __syncthreads();
    const int base = b * PPB;
#pragma unroll
    for (int i = 0; i < ITER; ++i) {
        const int p = base + i * 256 + t;
        const float x = qp[3*p], y = qp[3*p+1], z = qp[3*p+2];
        const unsigned slot = atomicAdd(&cur[bin_of(x, y, z)], 1u);
        sorted[slot] = make_float4(x, y, z, __uint_as_float((unsigned)p));
    }
}

// ------- sort stage 2: per-bin 64-bucket counting sort (6-bit sub-Morton) ---
__global__ __launch_bounds__(256) void binsort_k(float4* __restrict__ sorted,
                                                 const unsigned* __restrict__ binbase) {
    __shared__ float4        pts[BCAP];
    __shared__ unsigned char sk[BCAP];
    __shared__ unsigned      cnt[64];

    const int bin = blockIdx.x, t = threadIdx.x;
    const unsigned start = binbase[bin];
    const unsigned end   = (bin < NBIN - 1) ? binbase[bin + 1] : (unsigned)NPTS;
    const int n = (int)(end - start);
    if (n <= 1 || n > BCAP) return;   // oversize: keep stage-1 order (perf-only)

    if (t < 64) cnt[t] = 0u;
    __syncthreads();
#pragma unroll
    for (int r = 0; r < BCAP / 256; ++r) {
        const int i = r * 256 + t;
        if (i < n) {
            const float4 p = sorted[start + i];
            pts[i] = p;
            // 0.78125-cell local coords (2 bits/axis), coarse bit high
            const unsigned ux = (unsigned)(int)(p.x * 1.28f) & 3u;
            const unsigned uy = (unsigned)(int)(p.y * 1.28f) & 3u;
            const unsigned uz = (unsigned)(int)(p.z * 1.28f) & 3u;
            const unsigned s = (ux & 1u) | ((uy & 1u) << 1) | ((uz & 1u) << 2)
                             | ((ux >> 1) << 3) | ((uy >> 1) << 4) | ((uz >> 1) << 5);
            sk[i] = (unsigned char)s;
            atomicAdd(&cnt[s], 1u);
        }
    }
    __syncthreads();
    if (t == 0) {   // exclusive scan of 64 counters — trivial serial
        unsigned run = 0;
#pragma unroll
        for (int i = 0; i < 64; ++i) { const unsigned v = cnt[i]; cnt[i] = run; run += v; }
    }
    __syncthreads();
#pragma unroll
    for (int r = 0; r < BCAP / 256; ++r) {
        const int i = r * 256 + t;
        if (i < n) {
            const unsigned dest = atomicAdd(&cnt[sk[i]], 1u);
            sorted[start + dest] = pts[i];
        }
    }
}

// ---------------- main kernels ----------------
__global__ __launch_bounds__(256) void nhv_sorted_bm_k(
    const float4* __restrict__ sp, const float* __restrict__ feat,
    const int* __restrict__ fidx, const unsigned* __restrict__ bm,
    float* __restrict__ out)
{
    const int nwg = NPTS / 256;
    const int bid = blockIdx.x;
    const int swz = (bid & 7) * (nwg >> 3) + (bid >> 3);   // XCD spatial slabs
    const int j   = swz * 256 + (int)threadIdx.x;

    const f4 s = __builtin_nontemporal_load((const f4*)sp + j);
    float acc[NF];
    nhv_point_bm(s.x, s.y, s.z, feat, fidx, bm, acc);
    const unsigned n = __float_as_uint(s.w);

    f4* o = (f4*)(out + (size_t)n * NF);
    f4 lo = {acc[0], acc[1], acc[2], acc[3]};
    f4 hi = {acc[4], acc[5], acc[6], acc[7]};
    __builtin_nontemporal_store(lo, o);
    __builtin_nontemporal_store(hi, o + 1);
}

__global__ __launch_bounds__(256) void nhv_sorted_k(
    const float4* __restrict__ sp, const float* __restrict__ feat,
    const int* __restrict__ fidx, float* __restrict__ out)
{
    const int nwg = NPTS / 256;
    const int bid = blockIdx.x;
    const int swz = (bid & 7) * (nwg >> 3) + (bid >> 3);
    const int j   = swz * 256 + (int)threadIdx.x;

    const f4 s = __builtin_nontemporal_load((const f4*)sp + j);
    float acc[NF];
    nhv_point(s.x, s.y, s.z, feat, fidx, acc);
    const unsigned n = __float_as_uint(s.w);
    f4* o = (f4*)(out + (size_t)n * NF);
    f4 lo = {acc[0], acc[1], acc[2], acc[3]};
    f4 hi = {acc[4], acc[5], acc[6], acc[7]};
    __builtin_nontemporal_store(lo, o);
    __builtin_nontemporal_store(hi, o + 1);
}

__global__ __launch_bounds__(256) void nhv_direct_k(
    const float* __restrict__ qp, const float* __restrict__ feat,
    const int* __restrict__ fidx, float* __restrict__ out)
{
    const int n = blockIdx.x * 256 + threadIdx.x;
    if (n >= NPTS) return;
    float acc[NF];
    nhv_point(qp[3*n], qp[3*n+1], qp[3*n+2], feat, fidx, acc);
    float4* o = (float4*)(out + (size_t)n * NF);
    o[0] = make_float4(acc[0], acc[1], acc[2], acc[3]);
    o[1] = make_float4(acc[4], acc[5], acc[6], acc[7]);
}

extern "C" void kernel_launch(void* const* d_in, const int* in_sizes, int n_in,
                              void* d_out, int out_size, void* d_ws, size_t ws_size,
                              hipStream_t stream) {
    const float* qp   = (const float*)d_in[0];
    const float* feat = (const float*)d_in[1];
    const int*   fidx = (const int*)d_in[2];
    float*       out  = (float*)d_out;

    // hist (4 MB) + binbase (16 KB) live in d_out; main kernel fully
    // overwrites d_out afterwards (same stream, ordered) -> deterministic.
    unsigned* hist    = (unsigned*)d_out;
    unsigned* binbase = hist + (size_t)SB * NBIN;

    if (ws_size >= SORTED_BYTES + BM_BYTES) {
        float4*   sorted = (float4*)d_ws;
        unsigned* bm     = (unsigned*)((char*)d_ws + SORTED_BYTES);

        hipLaunchKernelGGL(bmbuild_k, dim3(LVLS * BMW_L / 256), dim3(256), 0, stream, fidx, bm);
        hipLaunchKernelGGL(hist_k,    dim3(SB),   dim3(256), 0, stream, qp, hist);
        hipLaunchKernelGGL(colscan_k, dim3(16),   dim3(256), 0, stream, hist, binbase);
        hipLaunchKernelGGL(binscan_k, dim3(1),    dim3(256), 0, stream, binbase);
        hipLaunchKernelGGL(scatter_k, dim3(SB),   dim3(256), 0, stream, qp, hist, binbase, sorted);
        hipLaunchKernelGGL(binsort_k, dim3(NBIN), dim3(256), 0, stream, sorted, binbase);
        hipLaunchKernelGGL(nhv_sorted_bm_k, dim3(NPTS/256), dim3(256), 0, stream,
                           sorted, feat, fidx, bm, out);
    } else if (ws_size >= SORTED_BYTES) {
        float4* sorted = (float4*)d_ws;
        hipLaunchKernelGGL(hist_k,    dim3(SB),   dim3(256), 0, stream, qp, hist);
        hipLaunchKernelGGL(colscan_k, dim3(16),   dim3(256), 0, stream, hist, binbase);
        hipLaunchKernelGGL(binscan_k, dim3(1),    dim3(256), 0, stream, binbase);
        hipLaunchKernelGGL(scatter_k, dim3(SB),   dim3(256), 0, stream, qp, hist, binbase, sorted);
        hipLaunchKernelGGL(binsort_k, dim3(NBIN), dim3(256), 0, stream, sorted, binbase);
        hipLaunchKernelGGL(nhv_sorted_k, dim3(NPTS/256), dim3(256), 0, stream,
                           sorted, feat, fidx, out);
    } else {
        hipLaunchKernelGGL(nhv_direct_k, dim3(NPTS/256), dim3(256), 0, stream,
                           qp, feat, fidx, out);
    }
}